// Round 17
// baseline (23.383 us; speedup 1.0000x reference)
//
#include <hip/hip_runtime.h>
#include <math.h>

// B=2, N=512, DIM=3, C_IN=64, C_OUT=64
// ws layout (floats): s[1024] | gm8[1024*128 (uint2 per co)]
#define WS_S   0
#define WS_GM8 1024

typedef unsigned int u32;
typedef float f32x2 __attribute__((ext_vector_type(2)));

static __device__ __forceinline__ u32 bf16b(float x) {
    u32 u = __builtin_bit_cast(u32, x);
    return (u + 0x7FFFu + ((u >> 16) & 1u)) >> 16;   // RNE to bf16
}
static __device__ __forceinline__ float blo(u32 b) {   // low bf16 -> f32
    return __builtin_bit_cast(float, b << 16);
}
static __device__ __forceinline__ float bhi(u32 b) {   // high bf16 -> f32
    return __builtin_bit_cast(float, b & 0xFFFF0000u);
}

// ---------------------------------------------------------------------------
// Prep, grid 256 x 256 (pure s/gm8 -- no out-zeroing needed anymore):
//  4 bj each:  s[bj] = sum_c ||geom[bj,:,c]||*norm_w[c] + norm_b
//              gm8[bj][co] = uint2{ bf16(a0)|bf16(a1)<<16, bf16(a2)<<16 }
// ---------------------------------------------------------------------------
__global__ __launch_bounds__(256) void prep_kernel(
    const float* __restrict__ geom,    // [1024,3,64]
    const float* __restrict__ theta,   // [65,64]
    const float* __restrict__ norm_w,  // [65]
    const float* __restrict__ norm_b,  // [1]
    float* __restrict__ s,             // [1024]
    uint2* __restrict__ gm8)           // [1024,64]
{
    const int bx   = blockIdx.x;
    const int sub  = threadIdx.x >> 6;  // which of 4 bj
    const int lane = threadIdx.x & 63;  // = c, and = co
    const int bj   = bx * 4 + sub;
    __shared__ float g[4][192];         // [d*64 + c]

    const float* gb = geom + (size_t)bj * 192;
    g[sub][lane]       = gb[lane];
    g[sub][lane + 64]  = gb[lane + 64];
    g[sub][lane + 128] = gb[lane + 128];
    __syncthreads();

    {
        float g0 = g[sub][lane], g1 = g[sub][64 + lane], g2 = g[sub][128 + lane];
        float t = sqrtf(g0 * g0 + g1 * g1 + g2 * g2) * norm_w[lane];
        for (int off = 32; off > 0; off >>= 1) t += __shfl_down(t, off);
        if (lane == 0) s[bj] = t + norm_b[0];
    }

    float a0 = 0.f, a1 = 0.f, a2 = 0.f;
    for (int c = 0; c < 64; ++c) {
        float th = theta[c * 64 + lane];
        a0 = fmaf(g[sub][c],       th, a0);
        a1 = fmaf(g[sub][64 + c],  th, a1);
        a2 = fmaf(g[sub][128 + c], th, a2);
    }
    uint2 w;
    w.x = bf16b(a0) | (bf16b(a1) << 16);
    w.y = bf16b(a2) << 16;
    gm8[(size_t)bj * 64 + lane] = w;
}

// ---------------------------------------------------------------------------
// Main, grid 512 = (b*256 + ip), 512 thr = 8 waves (16 waves/CU).
// Block = (b, i-PAIR) x FULL j -> every out element owned by exactly one
// block: direct store, NO atomics, NO out-zeroing. Wave = 64-j chunk x 2 i.
// Inner-pair math identical to R16 (broadcast b128 + pk_fma). gm stream
// doubles vs R16 (134 MB, +0.6us per R15 A/B) in exchange for dropping the
// epilogue atomics + prep zero pass + half the reduce traffic.
//   an = a*naf (s folded in pack);  w = relu(al*an + be*a)
//   acc_d += w * (gm_d + r_d*t64)
// ---------------------------------------------------------------------------
__global__ __launch_bounds__(512) void main_kernel(
    const float* __restrict__ adj,     // [1024,512]
    const float* __restrict__ rel,     // [1024,512,3]
    const float* __restrict__ emb,     // [1024,512]
    const float* __restrict__ s_arr,   // [1024]
    const uint2* __restrict__ gm8,     // [1024,64]
    const float* __restrict__ theta,   // [65,64]
    const float* __restrict__ norm_w,  // [65]
    const float* __restrict__ alpha,   // [64]
    const float* __restrict__ beta,    // [64]
    float* __restrict__ out)           // [1024,192]
{
    const int bx   = blockIdx.x;
    const int ip   = bx & 255;
    const int b    = bx >> 8;
    const int tid  = threadIdx.x;      // 0..511
    const int lane = tid & 63;         // co
    const int wv   = tid >> 6;         // 0..7
    const int bi0  = b * 512 + ip * 2;

    __shared__ uint4 pk_l[2][512];     // 16 KB, i-major
    __shared__ float red[8][384];      // 12 KB

    // ---- pack: t = il*512 + j, lane-contiguous b128 writes ----
    {
        const float nw64 = norm_w[64];
        #pragma unroll
        for (int u = 0; u < 2; ++u) {
            int t  = tid + u * 512;        // 0..1023
            int il = t >> 9;               // 0..1
            int j  = t & 511;
            size_t p = (size_t)(bi0 + il) * 512 + j;
            const float* rp = rel + p * 3;
            float r0 = rp[0], r1 = rp[1], r2 = rp[2];
            float a   = adj[p];
            float naf = s_arr[b * 512 + j]
                      + nw64 * sqrtf(r0 * r0 + r1 * r1 + r2 * r2) + emb[p];
            uint4 q;
            q.x = __builtin_bit_cast(u32, a * naf);
            q.y = __builtin_bit_cast(u32, a);
            q.z = bf16b(r0) | (bf16b(r1) << 16);
            q.w = bf16b(r2) << 16;
            pk_l[il][j] = q;
        }
    }
    __syncthreads();

    const float al  = alpha[lane];
    const float be  = beta[lane];
    const float t64 = theta[64 * 64 + lane];
    const f32x2 t64v = {t64, t64};

    const uint2* gmv = gm8 + (size_t)(b * 512 + wv * 64) * 64 + lane;

    f32x2 acc01[2];
    float acc2[2];
    #pragma unroll
    for (int il = 0; il < 2; ++il) { acc01[il] = (f32x2){0.f, 0.f}; acc2[il] = 0.f; }

    #pragma unroll 4
    for (int jj = 0; jj < 64; ++jj) {
        uint2 gw = gmv[(size_t)jj * 64];           // 8B coalesced
        const f32x2 g01 = {blo(gw.x), bhi(gw.x)};
        const float gz  = bhi(gw.y);
        #pragma unroll
        for (int il = 0; il < 2; ++il) {
            uint4 q = pk_l[il][wv * 64 + jj];      // broadcast b128
            float an = __builtin_bit_cast(float, q.x);
            float av = __builtin_bit_cast(float, q.y);
            f32x2 r01 = {blo(q.z), bhi(q.z)};
            float r2  = __builtin_bit_cast(float, q.w);
            float w  = fmaxf(fmaf(al, an, be * av), 0.f);
            f32x2 wv2 = {w, w};
            f32x2 t01 = __builtin_elementwise_fma(r01, t64v, g01);  // v_pk_fma
            acc01[il] = __builtin_elementwise_fma(wv2, t01, acc01[il]);
            acc2[il]  = fmaf(w, fmaf(r2, t64, gz), acc2[il]);
        }
    }

    // ---- 8-wave reduce (lane-contiguous b32, conflict-free) ----
    float* rw = &red[wv][lane];
    #pragma unroll
    for (int il = 0; il < 2; ++il) {
        rw[il * 192]       = acc01[il].x;
        rw[il * 192 + 64]  = acc01[il].y;
        rw[il * 192 + 128] = acc2[il];
    }
    __syncthreads();

    if (tid < 384) {
        float v = 0.f;
        #pragma unroll
        for (int w8 = 0; w8 < 8; ++w8) v += red[w8][tid];
        int il = tid / 192, r = tid - il * 192;
        out[(size_t)(bi0 + il) * 192 + r] = v;   // exclusive, direct store
    }
}

extern "C" void kernel_launch(void* const* d_in, const int* in_sizes, int n_in,
                              void* d_out, int out_size, void* d_ws, size_t ws_size,
                              hipStream_t stream) {
    const float* geom   = (const float*)d_in[0];
    const float* adj    = (const float*)d_in[1];
    const float* rel    = (const float*)d_in[2];
    const float* emb    = (const float*)d_in[3];
    const float* theta  = (const float*)d_in[4];
    const float* norm_w = (const float*)d_in[5];
    const float* norm_b = (const float*)d_in[6];
    const float* alpha  = (const float*)d_in[7];
    const float* beta   = (const float*)d_in[8];
    float* out = (float*)d_out;

    float* ws  = (float*)d_ws;
    float* s   = ws + WS_S;
    uint2* gm8 = (uint2*)(ws + WS_GM8);

    prep_kernel<<<256, 256, 0, stream>>>(geom, theta, norm_w, norm_b, s, gm8);
    main_kernel<<<512, 512, 0, stream>>>(adj, rel, emb, s, gm8, theta, norm_w,
                                         alpha, beta, out);
}